// Round 9
// baseline (228.217 us; speedup 1.0000x reference)
//
#include <hip/hip_runtime.h>

#define T1 256
#define SPLIT 8
#define LDSCAP 1024
#define OVF_MARK 0xFFFFFFFFu

#define T2 1024
#define BINS 4096
#define CAPF 4096
#define FLOOR_KEY 0xC0200000u   /* f2k(2.5f) */
#define FLOOR_BITS 0x40200000u  /* bits of +2.5f */
#define FLOOR_RANGE 0x3FE00000u /* 0x80000000 - 0x40200000: pos floats >= 2.5 (incl +Inf/+NaN) */
#define MARGIN 8u               /* ulps; fp32 division collapse is <= ~2 ulps */

__device__ __forceinline__ unsigned rotl32(unsigned x, unsigned r) {
  return (x << r) | (x >> (32u - r));
}

// Threefry-2x32, 20 rounds, key=(0,42); returns x0^x1 (jax_threefry_partitionable
// 32-bit random_bits; counts=(hi=0, lo=flat) since n < 2^32).
__device__ __forceinline__ unsigned threefry_xor_0_42(unsigned x0, unsigned x1) {
  const unsigned k0 = 0u, k1 = 42u, k2 = 0u ^ 42u ^ 0x1BD11BDAu;
  x0 += k0; x1 += k1;
#define TF_R(r) { x0 += x1; x1 = rotl32(x1, r); x1 ^= x0; }
  TF_R(13) TF_R(15) TF_R(26) TF_R(6)
  x0 += k1; x1 += k2 + 1u;
  TF_R(17) TF_R(29) TF_R(16) TF_R(24)
  x0 += k2; x1 += k0 + 2u;
  TF_R(13) TF_R(15) TF_R(26) TF_R(6)
  x0 += k0; x1 += k1 + 3u;
  TF_R(17) TF_R(29) TF_R(16) TF_R(24)
  x0 += k1; x1 += k2 + 4u;
  TF_R(13) TF_R(15) TF_R(26) TF_R(6)
  x0 += k2; x1 += k0 + 5u;
#undef TF_R
  return x0 ^ x1;
}

// Bit-exact jax.random.gumbel(key(42))[flat] under partitionable threefry.
__device__ __forceinline__ float gumbel_at(unsigned flat) {
  unsigned bits = threefry_xor_0_42(0u, flat);
  float fl = __uint_as_float((bits >> 9) | 0x3F800000u) - 1.0f;  // [0,1)
  const float tiny = 1.17549435e-38f;
  float u = fmaxf(fl + tiny, tiny);   // == JAX's max(tiny, fl*(1-tiny)+tiny) bitwise
  return -logf(-logf(u));
}

// Monotone float <-> uint key (order-preserving, bijective).
__device__ __forceinline__ unsigned f2k(float f) {
  unsigned b = __float_as_uint(f);
  return (b & 0x80000000u) ? ~b : (b ^ 0x80000000u);
}
__device__ __forceinline__ float k2f(unsigned k) {
  unsigned b = (k & 0x80000000u) ? (k ^ 0x80000000u) : ~k;
  return __uint_as_float(b);
}

// ---- Kernel 1: streaming filter, 4-deep load pipeline, per-chunk output ----
__global__ __launch_bounds__(T1, 8) void scan_kernel(
    const float* __restrict__ logits, unsigned* __restrict__ counts,
    unsigned* __restrict__ okeys, unsigned* __restrict__ oidxs, int V) {
  const int row = blockIdx.x >> 3;          // / SPLIT
  const int chunk = blockIdx.x & (SPLIT - 1);
  const int tid = threadIdx.x;
  const int nv4 = V >> 2;
  const int c4 = (nv4 + SPLIT - 1) / SPLIT;
  const int beg = chunk * c4;
  const int end = min(nv4, beg + c4);
  const float* rowp = logits + (size_t)row * (size_t)V;
  const float4* rowp4 = (const float4*)rowp;

  __shared__ unsigned skey[LDSCAP];
  __shared__ unsigned sidx[LDSCAP];
  __shared__ unsigned snc;
  if (tid == 0) snc = 0u;
  __syncthreads();

#define TEST1(vv, col) do {                                              \
    unsigned b_ = __float_as_uint(vv);                                   \
    if (__builtin_expect(b_ - FLOOR_BITS < FLOOR_RANGE, 0)) {            \
      unsigned p_ = atomicAdd(&snc, 1u);                                 \
      if (p_ < LDSCAP) { skey[p_] = b_ ^ 0x80000000u; sidx[p_] = (unsigned)(col); } \
    } } while (0)
#define TEST4(vv, i4) do {                                               \
    TEST1((vv).x, (i4) * 4 + 0); TEST1((vv).y, (i4) * 4 + 1);            \
    TEST1((vv).z, (i4) * 4 + 2); TEST1((vv).w, (i4) * 4 + 3); } while (0)

  int i = beg + tid;
  // 4-deep batched main loop: 4 independent loads in flight before any use
  for (; i + 3 * T1 < end; i += 4 * T1) {
    float4 v0 = rowp4[i];
    float4 v1 = rowp4[i + T1];
    float4 v2 = rowp4[i + 2 * T1];
    float4 v3 = rowp4[i + 3 * T1];
    TEST4(v0, i); TEST4(v1, i + T1); TEST4(v2, i + 2 * T1); TEST4(v3, i + 3 * T1);
  }
  for (; i < end; i += T1) { float4 v = rowp4[i]; TEST4(v, i); }
  if (chunk == SPLIT - 1) {                  // scalar tail (none for V=128000)
    for (int j = nv4 * 4 + tid; j < V; j += T1) TEST1(rowp[j], j);
  }
#undef TEST4
#undef TEST1
  __syncthreads();

  const unsigned nc = snc;
  const unsigned nb = min(nc, (unsigned)LDSCAP);
  if (tid == 0) counts[row * SPLIT + chunk] = (nc > (unsigned)LDSCAP) ? OVF_MARK : nc;
  unsigned* kout = okeys + (size_t)(row * SPLIT + chunk) * LDSCAP;
  unsigned* iout = oidxs + (size_t)(row * SPLIT + chunk) * LDSCAP;
  for (unsigned p = tid; p < nb; p += T1) { kout[p] = skey[p]; iout[p] = sidx[p]; }
}

// ---- Kernel 2: exact selection + Gumbel-argmax (embedded exact fallback) ----
__global__ __launch_bounds__(T2) void select_kernel(
    const float* __restrict__ logits, const float* __restrict__ temps,
    const int* __restrict__ topk_ptr, const unsigned* __restrict__ counts,
    const unsigned* __restrict__ okeys, const unsigned* __restrict__ oidxs,
    int* __restrict__ out, int V) {
  const int row = blockIdx.x;
  const int tid = threadIdx.x;
  const unsigned K = (unsigned)(*topk_ptr);
  const float t = temps[row];
  const unsigned rowBase = (unsigned)row * (unsigned)V;
  const float* rowp = logits + (size_t)row * (size_t)V;
  const float4* rowp4 = (const float4*)rowp;
  const int nv4 = V >> 2;

  __shared__ unsigned hist[BINS];          // fallback only
  __shared__ unsigned cand_key[CAPF];
  __shared__ unsigned cand_idx[CAPF];
  __shared__ float    rv[T2];
  __shared__ unsigned ri[T2];
  __shared__ unsigned soff[SPLIT + 1];
  __shared__ int      sovf;
  __shared__ unsigned ncand, sBstar, sAbove, sK50;

  if (tid == 0) {
    ncand = 0u; sBstar = 0u; sAbove = 0u; sK50 = 0u;
    unsigned s = 0; int ovf = 0;
    const unsigned* c8 = counts + row * SPLIT;
#pragma unroll
    for (int cch = 0; cch < SPLIT; ++cch) {
      unsigned n = c8[cch];
      if (n == OVF_MARK) { ovf = 1; n = 0u; }
      soff[cch] = s; s += n;
    }
    soff[SPLIT] = s; sovf = ovf;
  }
  __syncthreads();

  const unsigned total = soff[SPLIT];
  const bool tryFast = (!sovf && total >= K && total <= (unsigned)CAPF);
  unsigned c = 0;
  unsigned cntAbove = 0;

  if (tryFast) {
    c = total;
#pragma unroll
    for (int cch = 0; cch < SPLIT; ++cch) {
      const unsigned off = soff[cch];
      const unsigned nbc = soff[cch + 1] - off;
      const unsigned* kin = okeys + (size_t)(row * SPLIT + cch) * LDSCAP;
      const unsigned* iin = oidxs + (size_t)(row * SPLIT + cch) * LDSCAP;
      for (unsigned p = tid; p < nbc; p += T2) {
        cand_key[off + p] = kin[p];
        cand_idx[off + p] = iin[p];
      }
    }
    __syncthreads();
    for (unsigned i = tid; i < c; i += T2) {
      unsigned ki = cand_key[i];
      unsigned gt = 0, eq = 0;
      for (unsigned j = 0; j < c; ++j) {
        unsigned kj = cand_key[j];
        gt += (kj > ki) ? 1u : 0u;
        eq += (kj == ki) ? 1u : 0u;
      }
      if (gt < K && gt + eq >= K) sK50 = ki;   // unique tie-group; same-value writes
    }
    __syncthreads();
  }

  // Margin: every non-candidate is >= MARGIN ulps below the K-th key => cannot
  // tie s50 after fp32 division for any t. Else run the exact full fallback.
  const bool fastOK = tryFast && (sK50 >= FLOOR_KEY + MARGIN);

  float bestV = -INFINITY;
  unsigned bestI = 0xFFFFFFFFu;

  if (!fastOK) {
    // ============ Exact fallback: round-6 verified 3-phase algorithm ============
    for (int i = tid; i < BINS; i += T2) hist[i] = 0u;
    if (tid == 0) { ncand = 0u; sK50 = 0u; }
    __syncthreads();

    for (int i = tid; i < nv4; i += T2) {
      float4 v = rowp4[i];
      atomicAdd(&hist[f2k(v.x) >> 20], 1u);
      atomicAdd(&hist[f2k(v.y) >> 20], 1u);
      atomicAdd(&hist[f2k(v.z) >> 20], 1u);
      atomicAdd(&hist[f2k(v.w) >> 20], 1u);
    }
    for (int j = nv4 * 4 + tid; j < V; j += T2) atomicAdd(&hist[f2k(rowp[j]) >> 20], 1u);
    __syncthreads();

    if (tid < 64) {
      const int lane = tid;
      unsigned s = 0;
      for (int k = 0; k < 64; ++k) s += hist[lane * 64 + k];
      unsigned suf = s;
#pragma unroll
      for (int off = 1; off < 64; off <<= 1) {
        unsigned o = __shfl_down(suf, off);
        if (lane + off < 64) suf += o;
      }
      unsigned sufn = __shfl_down(suf, 1);
      if (lane == 63) sufn = 0u;
      if (suf >= K && sufn < K) {
        unsigned run = sufn;
        for (int k = 63; k >= 0; --k) {
          unsigned h = hist[lane * 64 + k];
          unsigned nr = run + h;
          if (run < K && nr >= K) { sBstar = (unsigned)(lane * 64 + k); sAbove = run; }
          run = nr;
        }
      }
    }
    __syncthreads();

    const unsigned Bstar = sBstar;
    cntAbove = sAbove;
    const unsigned long long binCeilP1 = ((unsigned long long)(Bstar + 1u)) << 20;
    const unsigned lowKey = (Bstar >= 1u) ? ((Bstar - 1u) << 20) : 0u;

    for (int i = tid; i < nv4; i += T2) {
      float4 v = rowp4[i];
      float f[4] = {v.x, v.y, v.z, v.w};
#pragma unroll
      for (int e = 0; e < 4; ++e) {
        unsigned key = f2k(f[e]);
        if (key < lowKey) continue;
        unsigned col = (unsigned)(i * 4 + e);
        if ((unsigned long long)key >= binCeilP1) {
          float sj = f[e] / t;
          float val = sj + gumbel_at(rowBase + col);
          if (val > bestV || (val == bestV && col < bestI)) { bestV = val; bestI = col; }
        } else {
          unsigned p = atomicAdd(&ncand, 1u);
          if (p < CAPF) { cand_key[p] = key; cand_idx[p] = col; }
        }
      }
    }
    for (int j = nv4 * 4 + tid; j < V; j += T2) {
      unsigned key = f2k(rowp[j]);
      if (key < lowKey) continue;
      if ((unsigned long long)key >= binCeilP1) {
        float sj = rowp[j] / t;
        float val = sj + gumbel_at(rowBase + (unsigned)j);
        if (val > bestV || (val == bestV && (unsigned)j < bestI)) { bestV = val; bestI = (unsigned)j; }
      } else {
        unsigned p = atomicAdd(&ncand, 1u);
        if (p < CAPF) { cand_key[p] = key; cand_idx[p] = (unsigned)j; }
      }
    }
    __syncthreads();

    c = min(ncand, (unsigned)CAPF);
    for (unsigned i = tid; i < c; i += T2) {
      unsigned ki = cand_key[i];
      unsigned gt = 0, eq = 0;
      for (unsigned j = 0; j < c; ++j) {
        unsigned kj = cand_key[j];
        gt += (kj > ki) ? 1u : 0u;
        eq += (kj == ki) ? 1u : 0u;
      }
      if (cntAbove + gt < K && cntAbove + gt + eq >= K) sK50 = ki;
    }
    __syncthreads();
  }

  // ---- Common: exact division-mask + Gumbel-argmax over LDS candidates ----
  const float s50 = k2f(sK50) / t;
  for (unsigned i = tid; i < c; i += T2) {
    unsigned col = cand_idx[i];
    if (col >= (unsigned)V) continue;
    float sj = k2f(cand_key[i]) / t;
    if (sj >= s50) {             // replicate `scaled < kth -> -inf` exactly
      float val = sj + gumbel_at(rowBase + col);
      if (val > bestV || (val == bestV && col < bestI)) { bestV = val; bestI = col; }
    }
  }

  // ---- Block argmax, first-index tie-break (matches jnp.argmax) ----
  rv[tid] = bestV; ri[tid] = bestI;
  __syncthreads();
  for (int off = T2 / 2; off > 0; off >>= 1) {
    if (tid < off) {
      float v2 = rv[tid + off]; unsigned i2 = ri[tid + off];
      if (v2 > rv[tid] || (v2 == rv[tid] && i2 < ri[tid])) { rv[tid] = v2; ri[tid] = i2; }
    }
    __syncthreads();
  }
  if (tid == 0) out[row] = (int)((ri[0] < (unsigned)V) ? ri[0] : 0u);
}

extern "C" void kernel_launch(void* const* d_in, const int* in_sizes, int n_in,
                              void* d_out, int out_size, void* d_ws, size_t ws_size,
                              hipStream_t stream) {
  const float* logits = (const float*)d_in[0];
  const float* temps  = (const float*)d_in[1];
  const int*   topk   = (const int*)d_in[2];
  int* out = (int*)d_out;

  const int B = in_sizes[1];              // 256
  const int V = in_sizes[0] / B;          // 128000

  // ws layout: counts[B*SPLIT] | keys[B*SPLIT*LDSCAP] | idxs[B*SPLIT*LDSCAP] (~17 MB)
  // Every slot is written every call -> no zeroing needed (graph-safe).
  unsigned* counts = (unsigned*)d_ws;
  unsigned* okeys = counts + (size_t)B * SPLIT;
  unsigned* oidxs = okeys + (size_t)B * SPLIT * LDSCAP;

  scan_kernel<<<B * SPLIT, T1, 0, stream>>>(logits, counts, okeys, oidxs, V);
  select_kernel<<<B, T2, 0, stream>>>(logits, temps, topk, counts, okeys, oidxs, out, V);
}

// Round 10
// 227.141 us; speedup vs baseline: 1.0047x; 1.0047x over previous
//
#include <hip/hip_runtime.h>

#define T1 256
#define SPLIT 8
#define DEPTH 8
#define LDSCAP 1024
#define OVF_MARK 0xFFFFFFFFu

#define T2 1024
#define BINS 4096
#define CAPF 4096
#define FLOOR_KEY 0xC0200000u   /* f2k(2.5f) */
#define FLOOR_BITS 0x40200000u  /* bits of +2.5f */
#define FLOOR_RANGE 0x3FE00000u /* 0x80000000 - 0x40200000: pos floats >= 2.5 (incl +Inf/+NaN) */
#define MARGIN 8u               /* ulps; fp32 division collapse is <= ~2 ulps */

__device__ __forceinline__ unsigned rotl32(unsigned x, unsigned r) {
  return (x << r) | (x >> (32u - r));
}

// Threefry-2x32, 20 rounds, key=(0,42); returns x0^x1 (jax_threefry_partitionable
// 32-bit random_bits; counts=(hi=0, lo=flat) since n < 2^32).
__device__ __forceinline__ unsigned threefry_xor_0_42(unsigned x0, unsigned x1) {
  const unsigned k0 = 0u, k1 = 42u, k2 = 0u ^ 42u ^ 0x1BD11BDAu;
  x0 += k0; x1 += k1;
#define TF_R(r) { x0 += x1; x1 = rotl32(x1, r); x1 ^= x0; }
  TF_R(13) TF_R(15) TF_R(26) TF_R(6)
  x0 += k1; x1 += k2 + 1u;
  TF_R(17) TF_R(29) TF_R(16) TF_R(24)
  x0 += k2; x1 += k0 + 2u;
  TF_R(13) TF_R(15) TF_R(26) TF_R(6)
  x0 += k0; x1 += k1 + 3u;
  TF_R(17) TF_R(29) TF_R(16) TF_R(24)
  x0 += k1; x1 += k2 + 4u;
  TF_R(13) TF_R(15) TF_R(26) TF_R(6)
  x0 += k2; x1 += k0 + 5u;
#undef TF_R
  return x0 ^ x1;
}

// Bit-exact jax.random.gumbel(key(42))[flat] under partitionable threefry.
__device__ __forceinline__ float gumbel_at(unsigned flat) {
  unsigned bits = threefry_xor_0_42(0u, flat);
  float fl = __uint_as_float((bits >> 9) | 0x3F800000u) - 1.0f;  // [0,1)
  const float tiny = 1.17549435e-38f;
  float u = fmaxf(fl + tiny, tiny);   // == JAX's max(tiny, fl*(1-tiny)+tiny) bitwise
  return -logf(-logf(u));
}

// Monotone float <-> uint key (order-preserving, bijective).
__device__ __forceinline__ unsigned f2k(float f) {
  unsigned b = __float_as_uint(f);
  return (b & 0x80000000u) ? ~b : (b ^ 0x80000000u);
}
__device__ __forceinline__ float k2f(unsigned k) {
  unsigned b = (k & 0x80000000u) ? (k ^ 0x80000000u) : ~k;
  return __uint_as_float(b);
}

// ---- Kernel 1: streaming filter. 8-deep explicit MLP + wave-ballot compaction ----
__global__ __launch_bounds__(T1, 4) void scan_kernel(
    const float* __restrict__ logits, unsigned* __restrict__ counts,
    unsigned* __restrict__ okeys, unsigned* __restrict__ oidxs, int V) {
  const int row = blockIdx.x >> 3;          // / SPLIT
  const int chunk = blockIdx.x & (SPLIT - 1);
  const int tid = threadIdx.x;
  const int lane = tid & 63;
  const int nv4 = V >> 2;
  const int c4 = nv4 / SPLIT;               // 4000 for V=128000
  const int beg = chunk * c4;
  const int sub = c4 / DEPTH;               // 500: 8 coalesced sub-stripes per chunk
  const float* rowp = logits + (size_t)row * (size_t)V;
  const float4* rowp4 = (const float4*)rowp;

  __shared__ unsigned skey[LDSCAP];
  __shared__ unsigned sidx[LDSCAP];
  __shared__ unsigned snc;
  if (tid == 0) snc = 0u;
  __syncthreads();

  // Ballot-compaction test: ~2 instr per all-reject column; one leader atomic per wave.
#define PROC1(fv, col) do {                                                  \
    unsigned b_ = __float_as_uint(fv);                                       \
    bool p_ = (b_ - FLOOR_BITS) < FLOOR_RANGE;                               \
    unsigned long long m_ = __ballot(p_);                                    \
    if (m_) {                                                                \
      int lead_ = __builtin_ctzll(m_);                                       \
      unsigned base_ = 0u;                                                   \
      if (lane == lead_) base_ = atomicAdd(&snc, (unsigned)__popcll(m_));    \
      base_ = __shfl(base_, lead_);                                          \
      if (p_) {                                                              \
        unsigned my_ = base_ + (unsigned)__popcll(m_ & ((1ull << lane) - 1ull)); \
        if (my_ < LDSCAP) { skey[my_] = b_ ^ 0x80000000u; sidx[my_] = (unsigned)(col); } \
      }                                                                      \
    } } while (0)
#define PROC4(vv, i4) do {                                                   \
    PROC1((vv).x, (i4) * 4 + 0); PROC1((vv).y, (i4) * 4 + 1);                \
    PROC1((vv).z, (i4) * 4 + 2); PROC1((vv).w, (i4) * 4 + 3); } while (0)

  // Main: every iteration issues 8 independent coalesced float4 loads (one per
  // sub-stripe) before any consumption — 8 KB per wave in flight.
  for (int off = tid; off < sub; off += T1) {
    const int i0 = beg + off;
    float4 v0 = rowp4[i0 + 0 * sub];
    float4 v1 = rowp4[i0 + 1 * sub];
    float4 v2 = rowp4[i0 + 2 * sub];
    float4 v3 = rowp4[i0 + 3 * sub];
    float4 v4 = rowp4[i0 + 4 * sub];
    float4 v5 = rowp4[i0 + 5 * sub];
    float4 v6 = rowp4[i0 + 6 * sub];
    float4 v7 = rowp4[i0 + 7 * sub];
    PROC4(v0, i0 + 0 * sub); PROC4(v1, i0 + 1 * sub);
    PROC4(v2, i0 + 2 * sub); PROC4(v3, i0 + 3 * sub);
    PROC4(v4, i0 + 4 * sub); PROC4(v5, i0 + 5 * sub);
    PROC4(v6, i0 + 6 * sub); PROC4(v7, i0 + 7 * sub);
  }
  // Remainders (c4 % DEPTH float4s; plus nv4 % SPLIT and V % 4 on the last chunk).
  for (int i = beg + DEPTH * sub + tid; i < beg + c4; i += T1) {
    float4 v = rowp4[i]; PROC4(v, i);
  }
  if (chunk == SPLIT - 1) {
    for (int i = SPLIT * c4 + tid; i < nv4; i += T1) { float4 v = rowp4[i]; PROC4(v, i); }
    for (int j = nv4 * 4 + tid; j < V; j += T1) PROC1(rowp[j], j);
  }
#undef PROC4
#undef PROC1
  __syncthreads();

  const unsigned nc = snc;
  const unsigned nb = min(nc, (unsigned)LDSCAP);
  if (tid == 0) counts[row * SPLIT + chunk] = (nc > (unsigned)LDSCAP) ? OVF_MARK : nc;
  unsigned* kout = okeys + (size_t)(row * SPLIT + chunk) * LDSCAP;
  unsigned* iout = oidxs + (size_t)(row * SPLIT + chunk) * LDSCAP;
  for (unsigned p = tid; p < nb; p += T1) { kout[p] = skey[p]; iout[p] = sidx[p]; }
}

// ---- Kernel 2: exact selection + Gumbel-argmax (embedded exact fallback) ----
__global__ __launch_bounds__(T2) void select_kernel(
    const float* __restrict__ logits, const float* __restrict__ temps,
    const int* __restrict__ topk_ptr, const unsigned* __restrict__ counts,
    const unsigned* __restrict__ okeys, const unsigned* __restrict__ oidxs,
    int* __restrict__ out, int V) {
  const int row = blockIdx.x;
  const int tid = threadIdx.x;
  const unsigned K = (unsigned)(*topk_ptr);
  const float t = temps[row];
  const unsigned rowBase = (unsigned)row * (unsigned)V;
  const float* rowp = logits + (size_t)row * (size_t)V;
  const float4* rowp4 = (const float4*)rowp;
  const int nv4 = V >> 2;

  __shared__ unsigned hist[BINS];          // fallback only
  __shared__ unsigned cand_key[CAPF];
  __shared__ unsigned cand_idx[CAPF];
  __shared__ float    rv[T2];
  __shared__ unsigned ri[T2];
  __shared__ unsigned soff[SPLIT + 1];
  __shared__ int      sovf;
  __shared__ unsigned ncand, sBstar, sAbove, sK50;

  if (tid == 0) {
    ncand = 0u; sBstar = 0u; sAbove = 0u; sK50 = 0u;
    unsigned s = 0; int ovf = 0;
    const unsigned* c8 = counts + row * SPLIT;
#pragma unroll
    for (int cch = 0; cch < SPLIT; ++cch) {
      unsigned n = c8[cch];
      if (n == OVF_MARK) { ovf = 1; n = 0u; }
      soff[cch] = s; s += n;
    }
    soff[SPLIT] = s; sovf = ovf;
  }
  __syncthreads();

  const unsigned total = soff[SPLIT];
  const bool tryFast = (!sovf && total >= K && total <= (unsigned)CAPF);
  unsigned c = 0;
  unsigned cntAbove = 0;

  if (tryFast) {
    c = total;
#pragma unroll
    for (int cch = 0; cch < SPLIT; ++cch) {
      const unsigned off = soff[cch];
      const unsigned nbc = soff[cch + 1] - off;
      const unsigned* kin = okeys + (size_t)(row * SPLIT + cch) * LDSCAP;
      const unsigned* iin = oidxs + (size_t)(row * SPLIT + cch) * LDSCAP;
      for (unsigned p = tid; p < nbc; p += T2) {
        cand_key[off + p] = kin[p];
        cand_idx[off + p] = iin[p];
      }
    }
    __syncthreads();
    for (unsigned i = tid; i < c; i += T2) {
      unsigned ki = cand_key[i];
      unsigned gt = 0, eq = 0;
      for (unsigned j = 0; j < c; ++j) {
        unsigned kj = cand_key[j];
        gt += (kj > ki) ? 1u : 0u;
        eq += (kj == ki) ? 1u : 0u;
      }
      if (gt < K && gt + eq >= K) sK50 = ki;   // unique tie-group; same-value writes
    }
    __syncthreads();
  }

  // Margin: every non-candidate is >= MARGIN ulps below the K-th key => cannot
  // tie s50 after fp32 division for any t. Else run the exact full fallback.
  const bool fastOK = tryFast && (sK50 >= FLOOR_KEY + MARGIN);

  float bestV = -INFINITY;
  unsigned bestI = 0xFFFFFFFFu;

  if (!fastOK) {
    // ============ Exact fallback: round-6 verified 3-phase algorithm ============
    for (int i = tid; i < BINS; i += T2) hist[i] = 0u;
    if (tid == 0) { ncand = 0u; sK50 = 0u; }
    __syncthreads();

    for (int i = tid; i < nv4; i += T2) {
      float4 v = rowp4[i];
      atomicAdd(&hist[f2k(v.x) >> 20], 1u);
      atomicAdd(&hist[f2k(v.y) >> 20], 1u);
      atomicAdd(&hist[f2k(v.z) >> 20], 1u);
      atomicAdd(&hist[f2k(v.w) >> 20], 1u);
    }
    for (int j = nv4 * 4 + tid; j < V; j += T2) atomicAdd(&hist[f2k(rowp[j]) >> 20], 1u);
    __syncthreads();

    if (tid < 64) {
      const int lane = tid;
      unsigned s = 0;
      for (int k = 0; k < 64; ++k) s += hist[lane * 64 + k];
      unsigned suf = s;
#pragma unroll
      for (int off = 1; off < 64; off <<= 1) {
        unsigned o = __shfl_down(suf, off);
        if (lane + off < 64) suf += o;
      }
      unsigned sufn = __shfl_down(suf, 1);
      if (lane == 63) sufn = 0u;
      if (suf >= K && sufn < K) {
        unsigned run = sufn;
        for (int k = 63; k >= 0; --k) {
          unsigned h = hist[lane * 64 + k];
          unsigned nr = run + h;
          if (run < K && nr >= K) { sBstar = (unsigned)(lane * 64 + k); sAbove = run; }
          run = nr;
        }
      }
    }
    __syncthreads();

    const unsigned Bstar = sBstar;
    cntAbove = sAbove;
    const unsigned long long binCeilP1 = ((unsigned long long)(Bstar + 1u)) << 20;
    const unsigned lowKey = (Bstar >= 1u) ? ((Bstar - 1u) << 20) : 0u;

    for (int i = tid; i < nv4; i += T2) {
      float4 v = rowp4[i];
      float f[4] = {v.x, v.y, v.z, v.w};
#pragma unroll
      for (int e = 0; e < 4; ++e) {
        unsigned key = f2k(f[e]);
        if (key < lowKey) continue;
        unsigned col = (unsigned)(i * 4 + e);
        if ((unsigned long long)key >= binCeilP1) {
          float sj = f[e] / t;
          float val = sj + gumbel_at(rowBase + col);
          if (val > bestV || (val == bestV && col < bestI)) { bestV = val; bestI = col; }
        } else {
          unsigned p = atomicAdd(&ncand, 1u);
          if (p < CAPF) { cand_key[p] = key; cand_idx[p] = col; }
        }
      }
    }
    for (int j = nv4 * 4 + tid; j < V; j += T2) {
      unsigned key = f2k(rowp[j]);
      if (key < lowKey) continue;
      if ((unsigned long long)key >= binCeilP1) {
        float sj = rowp[j] / t;
        float val = sj + gumbel_at(rowBase + (unsigned)j);
        if (val > bestV || (val == bestV && (unsigned)j < bestI)) { bestV = val; bestI = (unsigned)j; }
      } else {
        unsigned p = atomicAdd(&ncand, 1u);
        if (p < CAPF) { cand_key[p] = key; cand_idx[p] = (unsigned)j; }
      }
    }
    __syncthreads();

    c = min(ncand, (unsigned)CAPF);
    for (unsigned i = tid; i < c; i += T2) {
      unsigned ki = cand_key[i];
      unsigned gt = 0, eq = 0;
      for (unsigned j = 0; j < c; ++j) {
        unsigned kj = cand_key[j];
        gt += (kj > ki) ? 1u : 0u;
        eq += (kj == ki) ? 1u : 0u;
      }
      if (cntAbove + gt < K && cntAbove + gt + eq >= K) sK50 = ki;
    }
    __syncthreads();
  }

  // ---- Common: exact division-mask + Gumbel-argmax over LDS candidates ----
  const float s50 = k2f(sK50) / t;
  for (unsigned i = tid; i < c; i += T2) {
    unsigned col = cand_idx[i];
    if (col >= (unsigned)V) continue;
    float sj = k2f(cand_key[i]) / t;
    if (sj >= s50) {             // replicate `scaled < kth -> -inf` exactly
      float val = sj + gumbel_at(rowBase + col);
      if (val > bestV || (val == bestV && col < bestI)) { bestV = val; bestI = col; }
    }
  }

  // ---- Block argmax, first-index tie-break (matches jnp.argmax) ----
  rv[tid] = bestV; ri[tid] = bestI;
  __syncthreads();
  for (int off = T2 / 2; off > 0; off >>= 1) {
    if (tid < off) {
      float v2 = rv[tid + off]; unsigned i2 = ri[tid + off];
      if (v2 > rv[tid] || (v2 == rv[tid] && i2 < ri[tid])) { rv[tid] = v2; ri[tid] = i2; }
    }
    __syncthreads();
  }
  if (tid == 0) out[row] = (int)((ri[0] < (unsigned)V) ? ri[0] : 0u);
}

extern "C" void kernel_launch(void* const* d_in, const int* in_sizes, int n_in,
                              void* d_out, int out_size, void* d_ws, size_t ws_size,
                              hipStream_t stream) {
  const float* logits = (const float*)d_in[0];
  const float* temps  = (const float*)d_in[1];
  const int*   topk   = (const int*)d_in[2];
  int* out = (int*)d_out;

  const int B = in_sizes[1];              // 256
  const int V = in_sizes[0] / B;          // 128000

  // ws layout: counts[B*SPLIT] | keys[B*SPLIT*LDSCAP] | idxs[B*SPLIT*LDSCAP] (~17 MB)
  // Every slot is written every call -> no zeroing needed (graph-safe).
  unsigned* counts = (unsigned*)d_ws;
  unsigned* okeys = counts + (size_t)B * SPLIT;
  unsigned* oidxs = okeys + (size_t)B * SPLIT * LDSCAP;

  scan_kernel<<<B * SPLIT, T1, 0, stream>>>(logits, counts, okeys, oidxs, V);
  select_kernel<<<B, T2, 0, stream>>>(logits, temps, topk, counts, okeys, oidxs, out, V);
}